// Round 1
// baseline (695.630 us; speedup 1.0000x reference)
//
#include <hip/hip_runtime.h>
#include <math.h>

#define B_ 64
#define S_ 2048
#define H_ 1024
#define K_ 1024
#define M_ (B_*S_)   // 131072 rows of the big GEMM

using f32x4   = __attribute__((ext_vector_type(4))) float;
using bf16x8  = __attribute__((ext_vector_type(8))) __bf16;
using ushort8 = __attribute__((ext_vector_type(8))) unsigned short;

typedef __attribute__((address_space(1))) void gvoid_t;
typedef __attribute__((address_space(3))) void lvoid_t;

__device__ __forceinline__ unsigned short f2b(float f) {
  unsigned int u = __float_as_uint(f);
  u += 0x7fffu + ((u >> 16) & 1u);   // RNE
  return (unsigned short)(u >> 16);
}

__device__ __forceinline__ void async16(const void* g, void* l) {
  // 16B per lane, LDS dest = wave-uniform base + lane*16 (HW rule)
  __builtin_amdgcn_global_load_lds((gvoid_t*)g, (lvoid_t*)l, 16, 0, 0);
}

// ---------------------------------------------------------------- mask dtype
// flag: 0 = int32 {0,1}, 1 = bytes (bool), 2 = float32 {0,1.0}
__global__ void detect_mask(const unsigned int* __restrict__ m, int* __restrict__ flag) {
  __shared__ int red[256];
  int t = threadIdx.x;
  int f = 0;
  for (int i = 0; i < 32; ++i) {
    unsigned int w = m[t * 32 + i];          // first 32 KiB — safe for all dtypes
    if (w > 1u) f |= 1;                      // not plain int32 0/1
    if (w != 0u && w != 0x3f800000u) f |= 2; // not float 0.0/1.0
  }
  red[t] = f;
  __syncthreads();
  for (int o = 128; o > 0; o >>= 1) { if (t < o) red[t] |= red[t + o]; __syncthreads(); }
  if (t == 0) {
    int g = red[0];
    *flag = ((g & 1) == 0) ? 0 : (((g & 2) == 0) ? 2 : 1);
  }
}

// ---------------------------------------------------------------- Wk -> bf16
__global__ void convert_wk(const float* __restrict__ src, unsigned short* __restrict__ dst) {
  int i = blockIdx.x * blockDim.x + threadIdx.x;   // float4 index
  float4 v = ((const float4*)src)[i];
  ushort4 o;
  o.x = f2b(v.x); o.y = f2b(v.y); o.z = f2b(v.z); o.w = f2b(v.w);
  *(ushort4*)(dst + (size_t)i * 4) = o;
}

// ---------------------------------------------------------------- qp = query @ Wq.T
__global__ void qp_kernel(const float* __restrict__ query, const float* __restrict__ Wq,
                          float* __restrict__ qp) {
  __shared__ float qs[1024];
  const int b = blockIdx.x, t = threadIdx.x;
  ((float4*)qs)[t] = ((const float4*)(query + b * 1024))[t];
  __syncthreads();
#pragma unroll
  for (int i = 0; i < 4; ++i) {
    int h = t + i * 256;
    const float4* wr = (const float4*)(Wq + h * 1024);
    float s = 0.f;
    for (int q4 = 0; q4 < 256; ++q4) {
      float4 w = wr[q4];
      float4 q = ((const float4*)qs)[q4];
      s += w.x * q.x + w.y * q.y + w.z * q.z + w.w * q.w;
    }
    qp[b * 1024 + h] = s;
  }
}

// ---------------------------------------------------------------- fused GEMM + energy
__global__ __launch_bounds__(256) void gemm_energy(
    const float* __restrict__ keys,          // [M_][1024] f32
    const unsigned short* __restrict__ wk,   // [1024][1024] bf16 (B^T layout)
    const float* __restrict__ qp,            // [64][1024]
    const float* __restrict__ v,             // [1024]
    float* __restrict__ energy) {            // [M_]
  __shared__ __align__(16) unsigned short As[128 * 32];
  __shared__ __align__(16) unsigned short Bs[128 * 32];

  const int tid  = threadIdx.x;
  const int w    = tid >> 6;
  const int lane = tid & 63;

  // XCD-bijective swizzle: all 8 n-tiles of one m-tile consecutive on one XCD
  const int orig = blockIdx.x;                   // 0..8191
  const int wgid = (orig & 7) * 1024 + (orig >> 3);
  const int m0 = (wgid >> 3) * 128;
  const int n0 = (wgid & 7) * 128;

  const int wm = w >> 1, wn = w & 1;

  f32x4 acc[4][4] = {};

  int arow[2], acol[2];
#pragma unroll
  for (int i = 0; i < 2; ++i) {
    int c = tid + i * 256;
    arow[i] = c >> 2;
    acol[i] = (c & 3) * 8;
  }
  const float* Abase = keys + (size_t)m0 * K_;

  float4 pre[2][2];
#pragma unroll
  for (int i = 0; i < 2; ++i) {
    const float* p = Abase + arow[i] * K_ + acol[i];
    pre[i][0] = *(const float4*)p;
    pre[i][1] = *(const float4*)(p + 4);
  }

  for (int kt = 0; kt < K_ / 32; ++kt) {
    const int k0 = kt * 32;
#pragma unroll
    for (int i = 0; i < 2; ++i) {
      ushort8 u;
      u[0] = f2b(pre[i][0].x); u[1] = f2b(pre[i][0].y);
      u[2] = f2b(pre[i][0].z); u[3] = f2b(pre[i][0].w);
      u[4] = f2b(pre[i][1].x); u[5] = f2b(pre[i][1].y);
      u[6] = f2b(pre[i][1].z); u[7] = f2b(pre[i][1].w);
      *(ushort8*)(&As[arow[i] * 32 + acol[i]]) = u;
    }
#pragma unroll
    for (int j = 0; j < 2; ++j) {
      int flat = w * 1024 + j * 512 + lane * 8;
      const unsigned short* src = wk + (size_t)(n0 + (flat >> 5)) * K_ + k0 + (flat & 31);
      async16(src, &Bs[w * 1024 + j * 512]);
    }
    __syncthreads();
    if (kt + 1 < K_ / 32) {
#pragma unroll
      for (int i = 0; i < 2; ++i) {
        const float* p = Abase + arow[i] * K_ + (k0 + 32) + acol[i];
        pre[i][0] = *(const float4*)p;
        pre[i][1] = *(const float4*)(p + 4);
      }
    }
    const int kk = (lane >> 4) * 8;
    bf16x8 af[4], bf[4];
#pragma unroll
    for (int mi = 0; mi < 4; ++mi) {
      int r = wm * 64 + mi * 16 + (lane & 15);
      af[mi] = *(const bf16x8*)(&As[r * 32 + kk]);
    }
#pragma unroll
    for (int ni = 0; ni < 4; ++ni) {
      int r = wn * 64 + ni * 16 + (lane & 15);
      bf[ni] = *(const bf16x8*)(&Bs[r * 32 + kk]);
    }
#pragma unroll
    for (int mi = 0; mi < 4; ++mi)
#pragma unroll
      for (int ni = 0; ni < 4; ++ni)
        acc[mi][ni] = __builtin_amdgcn_mfma_f32_16x16x32_bf16(af[mi], bf[ni], acc[mi][ni], 0, 0, 0);
    __syncthreads();
  }

  // epilogue: C/D layout col = lane&15, row = (lane>>4)*4 + reg
  const int bb = m0 >> 11;
  float qpv[4], vv[4];
#pragma unroll
  for (int ni = 0; ni < 4; ++ni) {
    int h = n0 + wn * 64 + ni * 16 + (lane & 15);
    qpv[ni] = qp[bb * H_ + h];
    vv[ni]  = v[h];
  }
#pragma unroll
  for (int mi = 0; mi < 4; ++mi) {
    float ps[4] = {0.f, 0.f, 0.f, 0.f};
#pragma unroll
    for (int ni = 0; ni < 4; ++ni)
#pragma unroll
      for (int r = 0; r < 4; ++r)
        ps[r] += tanhf(acc[mi][ni][r] + qpv[ni]) * vv[ni];
#pragma unroll
    for (int off = 1; off < 16; off <<= 1)
#pragma unroll
      for (int r = 0; r < 4; ++r)
        ps[r] += __shfl_xor(ps[r], off, 64);
    if ((lane & 15) == 0) {
      int rowbase = m0 + wm * 64 + mi * 16 + (lane >> 4) * 4;
#pragma unroll
      for (int r = 0; r < 4; ++r)
        atomicAdd(&energy[rowbase + r], ps[r]);
    }
  }
}

// ---------------------------------------------------------------- masked softmax
__global__ void softmax_kernel(const float* __restrict__ energy, const void* __restrict__ mask,
                               const int* __restrict__ flag, float* __restrict__ attn) {
  __shared__ float red[256];
  const int b = blockIdx.x, t = threadIdx.x;
  const int fl = *flag;
  float e[8];
#pragma unroll
  for (int i = 0; i < 8; ++i) {
    int s = i * 256 + t;
    int idx = b * S_ + s;
    bool m;
    if (fl == 1)      m = ((const unsigned char*)mask)[idx] != 0;
    else if (fl == 2) m = ((const float*)mask)[idx] != 0.f;
    else              m = ((const int*)mask)[idx] != 0;
    e[i] = m ? -INFINITY : energy[idx];
  }
  float mx = e[0];
#pragma unroll
  for (int i = 1; i < 8; ++i) mx = fmaxf(mx, e[i]);
  red[t] = mx; __syncthreads();
  for (int o = 128; o > 0; o >>= 1) { if (t < o) red[t] = fmaxf(red[t], red[t + o]); __syncthreads(); }
  mx = red[0];
  __syncthreads();
  const bool any = (mx > -INFINITY);
  float p[8]; float sum = 0.f;
#pragma unroll
  for (int i = 0; i < 8; ++i) {
    p[i] = (any && e[i] > -INFINITY) ? __expf(e[i] - mx) : 0.f;
    sum += p[i];
  }
  red[t] = sum; __syncthreads();
  for (int o = 128; o > 0; o >>= 1) { if (t < o) red[t] += red[t + o]; __syncthreads(); }
  sum = red[0];
  const float inv = (sum > 0.f) ? 1.f / sum : 0.f;
#pragma unroll
  for (int i = 0; i < 8; ++i) attn[b * S_ + i * 256 + t] = p[i] * inv;
}

// ---------------------------------------------------------------- context = attn @ keys
__global__ void context_kernel(const float* __restrict__ attn, const float* __restrict__ keys,
                               float* __restrict__ ctx) {
  const int b = blockIdx.y;
  const int sc = blockIdx.x;          // 16 chunks of 128 s
  const int t = threadIdx.x;          // k = 4t..4t+3
  const float* kb = keys + ((size_t)b * S_ + sc * 128) * K_;
  const float* ab = attn + b * S_ + sc * 128;
  float4 acc = {0.f, 0.f, 0.f, 0.f};
  for (int s = 0; s < 128; ++s) {
    float a = ab[s];                   // block-uniform
    if (a != 0.f) {                    // skip padded positions entirely
      float4 kv = *(const float4*)(kb + (size_t)s * K_ + t * 4);
      acc.x += a * kv.x; acc.y += a * kv.y; acc.z += a * kv.z; acc.w += a * kv.w;
    }
  }
  float* cb = ctx + b * K_ + t * 4;
  atomicAdd(cb + 0, acc.x);
  atomicAdd(cb + 1, acc.y);
  atomicAdd(cb + 2, acc.z);
  atomicAdd(cb + 3, acc.w);
}

// ---------------------------------------------------------------- launch
extern "C" void kernel_launch(void* const* d_in, const int* in_sizes, int n_in,
                              void* d_out, int out_size, void* d_ws, size_t ws_size,
                              hipStream_t stream) {
  (void)in_sizes; (void)n_in; (void)out_size; (void)ws_size;
  const float* query = (const float*)d_in[0];
  const float* keys  = (const float*)d_in[1];
  const void*  mask  = d_in[2];
  const float* Wq    = (const float*)d_in[3];
  const float* Wk    = (const float*)d_in[4];
  const float* v     = (const float*)d_in[5];

  float* ctx  = (float*)d_out;             // [64][1024]
  float* attn = (float*)d_out + B_ * K_;   // [64][2048]

  char* ws = (char*)d_ws;
  float*          energy = (float*)ws;                              // 512 KiB
  float*          qp     = (float*)(ws + (512 << 10));              // 256 KiB
  unsigned short* wkb    = (unsigned short*)(ws + (768 << 10));     // 2 MiB
  int*            flag   = (int*)(ws + (768 << 10) + (2 << 20));

  hipMemsetAsync(energy, 0, (size_t)M_ * 4, stream);
  hipMemsetAsync(ctx, 0, (size_t)B_ * K_ * 4, stream);
  detect_mask<<<1, 256, 0, stream>>>((const unsigned int*)mask, flag);
  convert_wk<<<(H_ * K_ / 4) / 256, 256, 0, stream>>>(Wk, wkb);
  qp_kernel<<<B_, 256, 0, stream>>>(query, Wq, qp);
  gemm_energy<<<(M_ / 128) * (H_ / 128), 256, 0, stream>>>(keys, wkb, qp, v, energy);
  softmax_kernel<<<B_, 256, 0, stream>>>(energy, mask, flag, attn);
  context_kernel<<<dim3(S_ / 128, B_), 256, 0, stream>>>(attn, keys, ctx);
}